// Round 14
// baseline (193.254 us; speedup 1.0000x reference)
//
#include <hip/hip_runtime.h>
#include <hip/hip_bf16.h>

#define NN 256
#define HH 256

typedef __attribute__((ext_vector_type(8))) short short8;
typedef __attribute__((ext_vector_type(4))) float f32x4;

__device__ __forceinline__ ushort f2bf(float x) {
    __hip_bfloat16 h = __float2bfloat16(x);
    return *reinterpret_cast<ushort*>(&h);
}
__device__ __forceinline__ float bf2f(ushort u) {
    __hip_bfloat16 h = *reinterpret_cast<__hip_bfloat16*>(&u);
    return __bfloat162float(h);
}
template <int CTRL>
__device__ __forceinline__ float dpp_add(float x) {
    int y = __builtin_amdgcn_update_dpp(0, __float_as_int(x), CTRL, 0xF, 0xF, true);
    return x + __int_as_float(y);
}
template <int CTRL>
__device__ __forceinline__ float dpp_max(float x) {
    int y = __builtin_amdgcn_update_dpp(0, __float_as_int(x), CTRL, 0xF, 0xF, true);
    return fmaxf(x, __int_as_float(y));
}
__device__ __forceinline__ float red16(float v) {
    v = dpp_add<0xB1>(v); v = dpp_add<0x4E>(v);
    v = dpp_add<0x141>(v); v = dpp_add<0x140>(v);
    return v;
}
__device__ __forceinline__ float red16max(float v) {
    v = dpp_max<0xB1>(v); v = dpp_max<0x4E>(v);
    v = dpp_max<0x141>(v); v = dpp_max<0x140>(v);
    return v;
}

// ws (float offsets), total 899,072 floats = 3,596,288 B  (R10 layout)
#define WS_P   0        // P[256][64]
#define WS_Q   16384    // Q[256][64]
#define WS_T   32768    // T[256][256]
#define WS_WA  98304    // WA[4][256]
#define WS_WB  99328    // WB[4][256]
#define WS_WGT 100352   // WgT ushort[256][64]
#define WS_PV  108544   // PV[2][4][256][256]
#define WS_ML  632832   // ML[2][4][256][2]
#define WS_W2H 636928   // W2hi ushort[256f][1024k]
#define WS_W2L 768000   // W2lo ushort[256f][1024k]

// grid 272: [0,16) WA/WB | [16,80) W2 transpose | [80,144) P/Q | [144,208) WgT | [208,272) T
__global__ __launch_bounds__(256) void precompute_kernel(
    const float* __restrict__ ahs, const float* __restrict__ goal,
    const float* __restrict__ action, const float* __restrict__ Wd,
    const float* __restrict__ b_dist, const float* __restrict__ Wg,
    const float* __restrict__ w, const float* __restrict__ a,
    float* __restrict__ ws)
{
    const int b = blockIdx.x;
    const int t = threadIdx.x;
    const int wid  = t >> 6;
    const int lane = t & 63;
    float* P  = ws + WS_P;
    float* Q  = ws + WS_Q;
    float* T  = ws + WS_T;
    float* WA = ws + WS_WA;
    float* WB = ws + WS_WB;
    ushort* WgT  = (ushort*)(ws + WS_WGT);
    ushort* W2hi = (ushort*)(ws + WS_W2H);
    ushort* W2lo = (ushort*)(ws + WS_W2L);

    __shared__ __align__(16) float tile[64][65];

    if (b < 16) {
        const int z  = b >> 2;
        const int rg = b & 3;
        const int hbase = rg*64 + wid*16;
        const f32x4 aB = *(const f32x4*)(a + lane*4);
        const f32x4 aA = *(const f32x4*)(a + HH + lane*4);
#pragma unroll 4
        for (int rr = 0; rr < 16; ++rr) {
            const int h = hbase + rr;
            const f32x4 w4 = *(const f32x4*)(w + z*HH*HH + h*HH + lane*4);
            float dA = w4.x*aA.x + w4.y*aA.y + w4.z*aA.z + w4.w*aA.w;
            float dB = w4.x*aB.x + w4.y*aB.y + w4.z*aB.z + w4.w*aB.w;
#pragma unroll
            for (int off = 32; off; off >>= 1) {
                dA += __shfl_xor(dA, off);
                dB += __shfl_xor(dB, off);
            }
            if (lane == 0) { WA[z*HH + h] = dA; WB[z*HH + h] = dB; }
        }
    } else if (b < 80) {
        const int idx = b - 16;
        const int k0  = (idx >> 2) * 64;
        const int f0  = (idx & 3) * 64;
        const int ff  = t & 63;
#pragma unroll 4
        for (int i = 0; i < 16; ++i) {
            const int kk = i*4 + wid;
            tile[kk][ff] = w[(k0 + kk)*HH + f0 + ff];
        }
        __syncthreads();
#pragma unroll 4
        for (int i = 0; i < 16; ++i) {
            const int fl = i*4 + wid;
            float x = tile[ff][fl];
            ushort hi = f2bf(x);
            ushort lo = f2bf(x - bf2f(hi));
            W2hi[(size_t)(f0 + fl)*1024 + k0 + ff] = hi;
            W2lo[(size_t)(f0 + fl)*1024 + k0 + ff] = lo;
        }
    } else if (b < 144) {
        const int i = (b - 80)*4 + wid;
        const int d = lane;
        float a0 = action[2*i], a1 = action[2*i+1];
        float g0 = goal[2*i],   g1 = goal[2*i+1];
        P[i*64 + d] = a0*Wd[0*64+d] + a1*Wd[1*64+d]
                    + g0*Wd[2*64+d] + g1*Wd[3*64+d] + b_dist[d];
        Q[i*64 + d] = a0*Wd[4*64+d] + a1*Wd[5*64+d]
                    + g0*Wd[6*64+d] + g1*Wd[7*64+d];
    } else if (b < 208) {
        const int d = b - 144;
        WgT[t*64 + d] = f2bf(Wg[d*HH + t]);
    } else {
        const int idx = ((b - 208)*256 + t)*4;
        float4 v = *(const float4*)(ahs + idx);
        float4 o;
        o.x = tanhf(v.x); o.y = tanhf(v.y); o.z = tanhf(v.z); o.w = tanhf(v.w);
        *(float4*)(T + idx) = o;
    }
}

// grid 512: block = (n, half hh); j in [hh*128,+128), 8 one-barrier chunks of 16.
// Double-buffered cross-chunk prefetch of T-values and raw Q rows: the next
// chunk's 20 loads issue before this chunk's MFMA/epilogue/barrier (~400+ cyc
// of slack vs ~150 without). (256,2): no VGPR cap pain, no spills.
__global__ __launch_bounds__(256, 2) void gat_partial_kernel(
    const float* __restrict__ ahs, const float* __restrict__ ghs,
    const float* __restrict__ b_gate, float* __restrict__ ws)
{
    const int n    = blockIdx.x >> 1;
    const int hh   = blockIdx.x & 1;
    const int t    = threadIdx.x;
    const int wid  = t >> 6;
    const int lane = t & 63;
    const int quad = lane >> 4;
    const int l15  = lane & 15;
    const int zg   = quad;
    const int jj   = l15;
    const int n0   = wid * 64;

    const float* P  = ws + WS_P;
    const float* Q  = ws + WS_Q;
    const float* T  = ws + WS_T;
    const float* WA = ws + WS_WA;
    const float* WB = ws + WS_WB;
    const ushort* WgT = (const ushort*)(ws + WS_WGT);
    float* PV = ws + WS_PV;
    float* ML = ws + WS_ML;

    __shared__ __align__(16) float part[2][4][16][4];
    __shared__ __align__(16) float alpha_w[4][16][4];
    __shared__ __align__(16) float vred[16][260];

    int hcol[4];
#pragma unroll
    for (int nt = 0; nt < 4; ++nt) hcol[nt] = n0 + nt*16 + l15;

    short8 bfrag[4][2];
    float  wa_reg[4][4];
    float  bgv[4], gval[4];
#pragma unroll
    for (int nt = 0; nt < 4; ++nt) {
#pragma unroll
        for (int kh = 0; kh < 2; ++kh)
            bfrag[nt][kh] = *(const short8*)(WgT + hcol[nt]*64 + kh*32 + quad*8);
#pragma unroll
        for (int z = 0; z < 4; ++z) wa_reg[z][nt] = WA[z*HH + hcol[nt]];
        bgv[nt]  = b_gate[hcol[nt]];
        gval[nt] = ghs[n*HH + hcol[nt]];
    }

    float pnA[2][8];
#pragma unroll
    for (int kh = 0; kh < 2; ++kh) {
        *(f32x4*)&pnA[kh][0] = *(const f32x4*)(P + n*64 + kh*32 + quad*8);
        *(f32x4*)&pnA[kh][4] = *(const f32x4*)(P + n*64 + kh*32 + quad*8 + 4);
    }

    float vacc[4][4];
    {
        float av[4];
#pragma unroll
        for (int nt = 0; nt < 4; ++nt) av[nt] = ahs[n*HH + hcol[nt]];
#pragma unroll
        for (int z = 0; z < 4; ++z)
#pragma unroll
            for (int nt = 0; nt < 4; ++nt)
                vacc[z][nt] = (hh == 0 && quad == 0) ? av[nt] : 0.f;
    }

    // redundant per-wave softmax init: lane (zg,jj) sums h=jj*16..+16
    float cz_r, m_r, l_r;
    {
        float pc = 0.f, ps = 0.f;
        const int hb = jj*16;
#pragma unroll
        for (int i4 = 0; i4 < 4; ++i4) {
            f32x4 av = *(const f32x4*)(ahs + n*HH + hb + i4*4);
            f32x4 wb = *(const f32x4*)(WB + zg*HH + hb + i4*4);
            f32x4 wa = *(const f32x4*)(WA + zg*HH + hb + i4*4);
            pc = fmaf(av.x, wb.x, pc); pc = fmaf(av.y, wb.y, pc);
            pc = fmaf(av.z, wb.z, pc); pc = fmaf(av.w, wb.w, pc);
            ps = fmaf(av.x, wa.x, ps); ps = fmaf(av.y, wa.y, ps);
            ps = fmaf(av.z, wa.z, ps); ps = fmaf(av.w, wa.w, ps);
        }
        pc = red16(pc); ps = red16(ps);
        cz_r = pc;
        if (hh == 0) {
            float sc = pc + ps;
            m_r = sc > 0.f ? sc : 0.2f * sc;
            l_r = 1.0f;
        } else {
            m_r = -__builtin_inff();
            l_r = 0.0f;
        }
    }

    // double-buffered prefetch state
    float tv[2][4][4];
    f32x4 qr[2][4];
    {
        const int j0 = hh*128;
#pragma unroll
        for (int r = 0; r < 4; ++r) {
            const int jg = j0 + quad*4 + r;
#pragma unroll
            for (int nt = 0; nt < 4; ++nt)
                tv[0][nt][r] = T[jg*HH + hcol[nt]];
        }
        const float* qrow = Q + (j0 + l15)*64 + quad*8;
        qr[0][0] = *(const f32x4*)(qrow);
        qr[0][1] = *(const f32x4*)(qrow + 4);
        qr[0][2] = *(const f32x4*)(qrow + 32);
        qr[0][3] = *(const f32x4*)(qrow + 36);
    }

#pragma unroll
    for (int cc = 0; cc < 8; ++cc) {
        const int j0  = hh*128 + cc*16;
        const int par = cc & 1;
        const int nb  = par ^ 1;

        // issue next chunk's loads first (independent of all current compute)
        if (cc < 7) {
            const int jn = j0 + 16;
#pragma unroll
            for (int r = 0; r < 4; ++r) {
                const int jg = jn + quad*4 + r;
#pragma unroll
                for (int nt = 0; nt < 4; ++nt)
                    tv[nb][nt][r] = T[jg*HH + hcol[nt]];
            }
            const float* qrow = Q + (jn + l15)*64 + quad*8;
            qr[nb][0] = *(const f32x4*)(qrow);
            qr[nb][1] = *(const f32x4*)(qrow + 4);
            qr[nb][2] = *(const f32x4*)(qrow + 32);
            qr[nb][3] = *(const f32x4*)(qrow + 36);
        }

        // A-frags from prefetched Q + P
        short8 afrag[2];
#pragma unroll
        for (int kh = 0; kh < 2; ++kh) {
            f32x4 qa = qr[par][kh*2 + 0];
            f32x4 qb = qr[par][kh*2 + 1];
            ushort hv[8];
            hv[0] = f2bf(fmaxf(pnA[kh][0] + qa.x, 0.f));
            hv[1] = f2bf(fmaxf(pnA[kh][1] + qa.y, 0.f));
            hv[2] = f2bf(fmaxf(pnA[kh][2] + qa.z, 0.f));
            hv[3] = f2bf(fmaxf(pnA[kh][3] + qa.w, 0.f));
            hv[4] = f2bf(fmaxf(pnA[kh][4] + qb.x, 0.f));
            hv[5] = f2bf(fmaxf(pnA[kh][5] + qb.y, 0.f));
            hv[6] = f2bf(fmaxf(pnA[kh][6] + qb.z, 0.f));
            hv[7] = f2bf(fmaxf(pnA[kh][7] + qb.w, 0.f));
            afrag[kh] = *(short8*)hv;
        }

        f32x4 acc[4];
#pragma unroll
        for (int nt = 0; nt < 4; ++nt) {
            f32x4 a4 = (f32x4){0.f,0.f,0.f,0.f};
            a4 = __builtin_amdgcn_mfma_f32_16x16x32_bf16(afrag[0], bfrag[nt][0], a4, 0, 0, 0);
            a4 = __builtin_amdgcn_mfma_f32_16x16x32_bf16(afrag[1], bfrag[nt][1], a4, 0, 0, 0);
            acc[nt] = a4;
        }

        // gate epilogue (T prefetched a full chunk ago, diag from regs)
        float vals[4][4];
#pragma unroll
        for (int r = 0; r < 4; ++r) {
            const int jg = j0 + quad*4 + r;
            const bool diag = (jg == n);
#pragma unroll
            for (int nt = 0; nt < 4; ++nt) {
                float u = acc[nt][r] + bgv[nt];
                float g = 1.0f / (1.0f + __expf(-u));
                vals[nt][r] = diag ? gval[nt] : g * tv[par][nt][r];
            }
        }

        // score partials
#pragma unroll
        for (int z = 0; z < 4; ++z) {
            float pp[4];
#pragma unroll
            for (int r = 0; r < 4; ++r) {
                float s = 0.f;
#pragma unroll
                for (int nt = 0; nt < 4; ++nt)
                    s = fmaf(vals[nt][r], wa_reg[z][nt], s);
                pp[r] = red16(s);
            }
            if (l15 == z) {
#pragma unroll
                for (int r = 0; r < 4; ++r)
                    part[par][z][quad*4 + r][wid] = pp[r];
            }
        }
        __syncthreads();   // only barrier per chunk

        // redundant lane-parallel softmax
        float scl0, scl1, scl2, scl3;
        {
            f32x4 pr = *(const f32x4*)&part[par][zg][jj][0];
            float s = cz_r + ((pr.x + pr.y) + (pr.z + pr.w));
            float e = s > 0.f ? s : 0.2f * s;
            float mx = red16max(e);
            float m_new = fmaxf(m_r, mx);
            float at = __expf(e - m_new);
            float ss = red16(at);
            float scale = __expf(m_r - m_new);
            l_r = l_r * scale + ss;
            m_r = m_new;
            alpha_w[wid][jj][zg] = at;
            scl0 = __shfl(scale, 0);
            scl1 = __shfl(scale, 16);
            scl2 = __shfl(scale, 32);
            scl3 = __shfl(scale, 48);
        }
#pragma unroll
        for (int nt = 0; nt < 4; ++nt) {
            vacc[0][nt] *= scl0; vacc[1][nt] *= scl1;
            vacc[2][nt] *= scl2; vacc[3][nt] *= scl3;
        }
#pragma unroll
        for (int r = 0; r < 4; ++r) {
            f32x4 al = *(const f32x4*)&alpha_w[wid][quad*4 + r][0];
#pragma unroll
            for (int nt = 0; nt < 4; ++nt) {
                float v = vals[nt][r];
                vacc[0][nt] = fmaf(al.x, v, vacc[0][nt]);
                vacc[1][nt] = fmaf(al.y, v, vacc[1][nt]);
                vacc[2][nt] = fmaf(al.z, v, vacc[2][nt]);
                vacc[3][nt] = fmaf(al.w, v, vacc[3][nt]);
            }
        }
    }

    // cross-quad reduce, write PV + ML
#pragma unroll
    for (int z = 0; z < 4; ++z)
#pragma unroll
        for (int nt = 0; nt < 4; ++nt)
            vred[quad*4 + z][hcol[nt]] = vacc[z][nt];
    __syncthreads();
#pragma unroll
    for (int z = 0; z < 4; ++z) {
        float s = (vred[0*4+z][t] + vred[1*4+z][t]) + (vred[2*4+z][t] + vred[3*4+z][t]);
        PV[((size_t)(hh*4 + z)*NN + n)*HH + t] = s;
    }
    if (wid == 0 && l15 == 0) {
        ML[((hh*4 + zg)*NN + n)*2 + 0] = m_r;
        ML[((hh*4 + zg)*NN + n)*2 + 1] = l_r;
    }
}

// grid 64: (16 n-tiles) x (4 f-tiles of 64). Fused 2-half merge + split-bf16 MFMA.
__global__ __launch_bounds__(256) void gat_out_kernel(
    const float* __restrict__ bias, const float* __restrict__ ws,
    float* __restrict__ out)
{
    const int n0 = (blockIdx.x >> 2) * 16;
    const int f0 = (blockIdx.x & 3) * 64;
    const int t    = threadIdx.x;
    const int wid  = t >> 6;
    const int lane = t & 63;
    const int quad = lane >> 4;
    const int l15  = lane & 15;

    const float* PV = ws + WS_PV;
    const float* ML = ws + WS_ML;
    const ushort* W2hi = (const ushort*)(ws + WS_W2H);
    const ushort* W2lo = (const ushort*)(ws + WS_W2L);

    __shared__ __align__(16) float redc[3*4*16*16];
    __shared__ __align__(16) float sq[16][4][2];

    // merge scales: t = n_i*8 + z*2 + q (t < 128); q-pairs adjacent lanes
    if (t < 128) {
        const int n_i = t >> 3, z = (t >> 1) & 3, q = t & 1;
        float m = ML[((q*4 + z)*NN + n0 + n_i)*2 + 0];
        float l = ML[((q*4 + z)*NN + n0 + n_i)*2 + 1];
        float mm = fmaxf(m, __shfl_xor(m, 1));
        float s  = __expf(m - mm);
        float ls = l * s;
        ls += __shfl_xor(ls, 1);
        sq[n_i][z][q] = s / ls;
    }
    __syncthreads();

    // wave wid owns z=wid (k stripe [wid*256,+256)); A-frags in registers
    f32x4 acc[4];
#pragma unroll
    for (int nt = 0; nt < 4; ++nt) acc[nt] = (f32x4){0.f,0.f,0.f,0.f};

    const float s0 = sq[l15][wid][0];
    const float s1 = sq[l15][wid][1];
    const float* pv0 = PV + ((size_t)(0*4 + wid)*NN + n0 + l15)*HH;
    const float* pv1 = PV + ((size_t)(1*4 + wid)*NN + n0 + l15)*HH;

    for (int ks = 0; ks < 8; ++ks) {
        const int kp = ks*32 + quad*8;
        f32x4 p0a = *(const f32x4*)(pv0 + kp);
        f32x4 p0b = *(const f32x4*)(pv0 + kp + 4);
        f32x4 p1a = *(const f32x4*)(pv1 + kp);
        f32x4 p1b = *(const f32x4*)(pv1 + kp + 4);
        float v[8];
        v[0] = s0*p0a.x + s1*p1a.x; v[1] = s0*p0a.y + s1*p1a.y;
        v[2] = s0*p0a.z + s1*p1a.z; v[3] = s0*p0a.w + s1*p1a.w;
        v[4] = s0*p0b.x + s1*p1b.x; v[5] = s0*p0b.y + s1*p1b.y;
        v[6] = s0*p0b.z + s1*p1b.z; v[7] = s0*p0b.w + s1*p1b.w;
        ushort hi[8], lo[8];
#pragma unroll
        for (int c = 0; c < 8; ++c) {
            hi[c] = f2bf(v[c]);
            lo[c] = f2bf(v[c] - bf2f(hi[c]));
        }
        short8 ah = *(short8*)hi;
        short8 al = *(short8*)lo;
        const int kg = wid*256 + kp;
#pragma unroll
        for (int nt = 0; nt < 4; ++nt) {
            const size_t boff = (size_t)(f0 + nt*16 + l15)*1024 + kg;
            short8 bh = *(const short8*)(W2hi + boff);
            short8 bl = *(const short8*)(W2lo + boff);
            acc[nt] = __builtin_amdgcn_mfma_f32_16x16x32_bf16(ah, bh, acc[nt], 0, 0, 0);
            acc[nt] = __builtin_amdgcn_mfma_f32_16x16x32_bf16(ah, bl, acc[nt], 0, 0, 0);
            acc[nt] = __builtin_amdgcn_mfma_f32_16x16x32_bf16(al, bh, acc[nt], 0, 0, 0);
        }
    }
    __syncthreads();

    if (wid > 0) {
#pragma unroll
        for (int nt = 0; nt < 4; ++nt)
#pragma unroll
            for (int r = 0; r < 4; ++r)
                redc[(((wid-1)*4 + nt)*16 + quad*4 + r)*16 + l15] = acc[nt][r];
    }
    __syncthreads();
    if (wid == 0) {
#pragma unroll
        for (int nt = 0; nt < 4; ++nt) {
            const int f = f0 + nt*16 + l15;
            float bv = bias[f];
#pragma unroll
            for (int r = 0; r < 4; ++r) {
                const int row = quad*4 + r;
                float s = acc[nt][r]
                        + redc[((0*4 + nt)*16 + row)*16 + l15]
                        + redc[((1*4 + nt)*16 + row)*16 + l15]
                        + redc[((2*4 + nt)*16 + row)*16 + l15];
                out[(size_t)(n0 + row)*HH + f] = fmaxf(0.25f * s, 0.f) + bv;
            }
        }
    }
}

extern "C" void kernel_launch(void* const* d_in, const int* in_sizes, int n_in,
                              void* d_out, int out_size, void* d_ws, size_t ws_size,
                              hipStream_t stream)
{
    const float* ahs    = (const float*)d_in[0];
    const float* ghs    = (const float*)d_in[1];
    const float* goal   = (const float*)d_in[2];
    const float* action = (const float*)d_in[3];
    const float* Wd     = (const float*)d_in[4];
    const float* b_dist = (const float*)d_in[5];
    const float* Wg     = (const float*)d_in[6];
    const float* b_gate = (const float*)d_in[7];
    const float* w      = (const float*)d_in[8];
    const float* a      = (const float*)d_in[9];
    const float* bias   = (const float*)d_in[10];
    float* ws   = (float*)d_ws;     // needs 3,596,288 bytes
    float* outp = (float*)d_out;

    precompute_kernel<<<272, 256, 0, stream>>>(ahs, goal, action, Wd, b_dist, Wg, w, a, ws);
    gat_partial_kernel<<<512, 256, 0, stream>>>(ahs, ghs, b_gate, ws);
    gat_out_kernel<<<64, 256, 0, stream>>>(bias, ws, outp);
}

// Round 15
// 126.591 us; speedup vs baseline: 1.5266x; 1.5266x over previous
//
#include <hip/hip_runtime.h>
#include <hip/hip_bf16.h>

#define NN 256
#define HH 256

typedef __attribute__((ext_vector_type(8))) short short8;
typedef __attribute__((ext_vector_type(4))) float f32x4;

__device__ __forceinline__ ushort f2bf(float x) {
    __hip_bfloat16 h = __float2bfloat16(x);
    return *reinterpret_cast<ushort*>(&h);
}
__device__ __forceinline__ float bf2f(ushort u) {
    __hip_bfloat16 h = *reinterpret_cast<__hip_bfloat16*>(&u);
    return __bfloat162float(h);
}
template <int CTRL>
__device__ __forceinline__ float dpp_add(float x) {
    int y = __builtin_amdgcn_update_dpp(0, __float_as_int(x), CTRL, 0xF, 0xF, true);
    return x + __int_as_float(y);
}
template <int CTRL>
__device__ __forceinline__ float dpp_max(float x) {
    int y = __builtin_amdgcn_update_dpp(0, __float_as_int(x), CTRL, 0xF, 0xF, true);
    return fmaxf(x, __int_as_float(y));
}
__device__ __forceinline__ float red16(float v) {
    v = dpp_add<0xB1>(v); v = dpp_add<0x4E>(v);
    v = dpp_add<0x141>(v); v = dpp_add<0x140>(v);
    return v;
}
__device__ __forceinline__ float red16max(float v) {
    v = dpp_max<0xB1>(v); v = dpp_max<0x4E>(v);
    v = dpp_max<0x141>(v); v = dpp_max<0x140>(v);
    return v;
}

// ws (float offsets), total 899,072 floats = 3,596,288 B
#define WS_P   0        // P[256][64]
#define WS_Q   16384    // Q[256][64]
#define WS_T   32768    // T[256][256]
#define WS_WA  98304    // WA[4][256]
#define WS_WB  99328    // WB[4][256]
#define WS_WGT 100352   // WgT ushort[256][64]
#define WS_PV  108544   // PV[2][4][256][256]
#define WS_ML  632832   // ML[2][4][256][2]
#define WS_W2H 636928   // W2hi ushort[256f][1024k]
#define WS_W2L 768000   // W2lo ushort[256f][1024k]

// grid 272: [0,16) WA/WB | [16,80) W2 transpose | [80,144) P/Q | [144,208) WgT | [208,272) T
__global__ __launch_bounds__(256) void precompute_kernel(
    const float* __restrict__ ahs, const float* __restrict__ goal,
    const float* __restrict__ action, const float* __restrict__ Wd,
    const float* __restrict__ b_dist, const float* __restrict__ Wg,
    const float* __restrict__ w, const float* __restrict__ a,
    float* __restrict__ ws)
{
    const int b = blockIdx.x;
    const int t = threadIdx.x;
    const int wid  = t >> 6;
    const int lane = t & 63;
    float* P  = ws + WS_P;
    float* Q  = ws + WS_Q;
    float* T  = ws + WS_T;
    float* WA = ws + WS_WA;
    float* WB = ws + WS_WB;
    ushort* WgT  = (ushort*)(ws + WS_WGT);
    ushort* W2hi = (ushort*)(ws + WS_W2H);
    ushort* W2lo = (ushort*)(ws + WS_W2L);

    __shared__ __align__(16) float tile[64][65];

    if (b < 16) {
        const int z  = b >> 2;
        const int rg = b & 3;
        const int hbase = rg*64 + wid*16;
        const f32x4 aB = *(const f32x4*)(a + lane*4);
        const f32x4 aA = *(const f32x4*)(a + HH + lane*4);
#pragma unroll 4
        for (int rr = 0; rr < 16; ++rr) {
            const int h = hbase + rr;
            const f32x4 w4 = *(const f32x4*)(w + z*HH*HH + h*HH + lane*4);
            float dA = w4.x*aA.x + w4.y*aA.y + w4.z*aA.z + w4.w*aA.w;
            float dB = w4.x*aB.x + w4.y*aB.y + w4.z*aB.z + w4.w*aB.w;
#pragma unroll
            for (int off = 32; off; off >>= 1) {
                dA += __shfl_xor(dA, off);
                dB += __shfl_xor(dB, off);
            }
            if (lane == 0) { WA[z*HH + h] = dA; WB[z*HH + h] = dB; }
        }
    } else if (b < 80) {
        const int idx = b - 16;
        const int k0  = (idx >> 2) * 64;
        const int f0  = (idx & 3) * 64;
        const int ff  = t & 63;
#pragma unroll 4
        for (int i = 0; i < 16; ++i) {
            const int kk = i*4 + wid;
            tile[kk][ff] = w[(k0 + kk)*HH + f0 + ff];
        }
        __syncthreads();
#pragma unroll 4
        for (int i = 0; i < 16; ++i) {
            const int fl = i*4 + wid;
            float x = tile[ff][fl];
            ushort hi = f2bf(x);
            ushort lo = f2bf(x - bf2f(hi));
            W2hi[(size_t)(f0 + fl)*1024 + k0 + ff] = hi;
            W2lo[(size_t)(f0 + fl)*1024 + k0 + ff] = lo;
        }
    } else if (b < 144) {
        const int i = (b - 80)*4 + wid;
        const int d = lane;
        float a0 = action[2*i], a1 = action[2*i+1];
        float g0 = goal[2*i],   g1 = goal[2*i+1];
        P[i*64 + d] = a0*Wd[0*64+d] + a1*Wd[1*64+d]
                    + g0*Wd[2*64+d] + g1*Wd[3*64+d] + b_dist[d];
        Q[i*64 + d] = a0*Wd[4*64+d] + a1*Wd[5*64+d]
                    + g0*Wd[6*64+d] + g1*Wd[7*64+d];
    } else if (b < 208) {
        const int d = b - 144;
        WgT[t*64 + d] = f2bf(Wg[d*HH + t]);
    } else {
        const int idx = ((b - 208)*256 + t)*4;
        float4 v = *(const float4*)(ahs + idx);
        float4 o;
        o.x = tanhf(v.x); o.y = tanhf(v.y); o.z = tanhf(v.z); o.w = tanhf(v.w);
        *(float4*)(T + idx) = o;
    }
}

// grid 512: block = (n, half hh); j in [hh*128, +128), 8 one-barrier chunks of 16.
// B-fragments persistent in registers; (256,2) -> 256-VGPR budget, no spills.
__global__ __launch_bounds__(256, 2) void gat_partial_kernel(
    const float* __restrict__ ahs, const float* __restrict__ ghs,
    const float* __restrict__ b_gate, float* __restrict__ ws)
{
    const int n    = blockIdx.x >> 1;
    const int hh   = blockIdx.x & 1;
    const int t    = threadIdx.x;
    const int wid  = t >> 6;
    const int lane = t & 63;
    const int quad = lane >> 4;
    const int l15  = lane & 15;
    const int zg   = quad;
    const int jj   = l15;
    const int n0   = wid * 64;

    const float* P  = ws + WS_P;
    const float* Q  = ws + WS_Q;
    const float* T  = ws + WS_T;
    const float* WA = ws + WS_WA;
    const float* WB = ws + WS_WB;
    const ushort* WgT = (const ushort*)(ws + WS_WGT);
    float* PV = ws + WS_PV;
    float* ML = ws + WS_ML;

    __shared__ __align__(16) float part[2][4][16][4];
    __shared__ __align__(16) float alpha_w[4][16][4];
    __shared__ __align__(16) float vred[16][260];

    int hcol[4];
#pragma unroll
    for (int nt = 0; nt < 4; ++nt) hcol[nt] = n0 + nt*16 + l15;

    short8 bfrag[4][2];
    float  wa_reg[4][4];
    float  bgv[4], gval[4];
#pragma unroll
    for (int nt = 0; nt < 4; ++nt) {
#pragma unroll
        for (int kh = 0; kh < 2; ++kh)
            bfrag[nt][kh] = *(const short8*)(WgT + hcol[nt]*64 + kh*32 + quad*8);
#pragma unroll
        for (int z = 0; z < 4; ++z) wa_reg[z][nt] = WA[z*HH + hcol[nt]];
        bgv[nt]  = b_gate[hcol[nt]];
        gval[nt] = ghs[n*HH + hcol[nt]];
    }

    float pnA[2][8];
#pragma unroll
    for (int kh = 0; kh < 2; ++kh) {
        *(f32x4*)&pnA[kh][0] = *(const f32x4*)(P + n*64 + kh*32 + quad*8);
        *(f32x4*)&pnA[kh][4] = *(const f32x4*)(P + n*64 + kh*32 + quad*8 + 4);
    }

    float vacc[4][4];
    {
        float av[4];
#pragma unroll
        for (int nt = 0; nt < 4; ++nt) av[nt] = ahs[n*HH + hcol[nt]];
#pragma unroll
        for (int z = 0; z < 4; ++z)
#pragma unroll
            for (int nt = 0; nt < 4; ++nt)
                vacc[z][nt] = (hh == 0 && quad == 0) ? av[nt] : 0.f;
    }

    // redundant per-wave softmax init: lane (zg,jj) sums h=jj*16..+16
    float cz_r, m_r, l_r;
    {
        float pc = 0.f, ps = 0.f;
        const int hb = jj*16;
#pragma unroll
        for (int i4 = 0; i4 < 4; ++i4) {
            f32x4 av = *(const f32x4*)(ahs + n*HH + hb + i4*4);
            f32x4 wb = *(const f32x4*)(WB + zg*HH + hb + i4*4);
            f32x4 wa = *(const f32x4*)(WA + zg*HH + hb + i4*4);
            pc = fmaf(av.x, wb.x, pc); pc = fmaf(av.y, wb.y, pc);
            pc = fmaf(av.z, wb.z, pc); pc = fmaf(av.w, wb.w, pc);
            ps = fmaf(av.x, wa.x, ps); ps = fmaf(av.y, wa.y, ps);
            ps = fmaf(av.z, wa.z, ps); ps = fmaf(av.w, wa.w, ps);
        }
        pc = red16(pc); ps = red16(ps);
        cz_r = pc;
        if (hh == 0) {
            float sc = pc + ps;
            m_r = sc > 0.f ? sc : 0.2f * sc;
            l_r = 1.0f;
        } else {
            m_r = -__builtin_inff();
            l_r = 0.0f;
        }
    }

    for (int cc = 0; cc < 8; ++cc) {
        const int j0  = hh*128 + cc*16;
        const int par = cc & 1;

        // T prefetch
        float tval[4][4];
#pragma unroll
        for (int r = 0; r < 4; ++r) {
            const int jg = j0 + quad*4 + r;
#pragma unroll
            for (int nt = 0; nt < 4; ++nt)
                tval[nt][r] = T[jg*HH + hcol[nt]];
        }

        // A-frags from Q + P
        short8 afrag[2];
#pragma unroll
        for (int kh = 0; kh < 2; ++kh) {
            const float* qrow = Q + (j0 + l15)*64 + kh*32 + quad*8;
            f32x4 qa = *(const f32x4*)qrow;
            f32x4 qb = *(const f32x4*)(qrow + 4);
            ushort hv[8];
            hv[0] = f2bf(fmaxf(pnA[kh][0] + qa.x, 0.f));
            hv[1] = f2bf(fmaxf(pnA[kh][1] + qa.y, 0.f));
            hv[2] = f2bf(fmaxf(pnA[kh][2] + qa.z, 0.f));
            hv[3] = f2bf(fmaxf(pnA[kh][3] + qa.w, 0.f));
            hv[4] = f2bf(fmaxf(pnA[kh][4] + qb.x, 0.f));
            hv[5] = f2bf(fmaxf(pnA[kh][5] + qb.y, 0.f));
            hv[6] = f2bf(fmaxf(pnA[kh][6] + qb.z, 0.f));
            hv[7] = f2bf(fmaxf(pnA[kh][7] + qb.w, 0.f));
            afrag[kh] = *(short8*)hv;
        }

        f32x4 acc[4];
#pragma unroll
        for (int nt = 0; nt < 4; ++nt) {
            f32x4 a4 = (f32x4){0.f,0.f,0.f,0.f};
            a4 = __builtin_amdgcn_mfma_f32_16x16x32_bf16(afrag[0], bfrag[nt][0], a4, 0, 0, 0);
            a4 = __builtin_amdgcn_mfma_f32_16x16x32_bf16(afrag[1], bfrag[nt][1], a4, 0, 0, 0);
            acc[nt] = a4;
        }

        // gate epilogue (T resident, diag from regs)
        float vals[4][4];
#pragma unroll
        for (int r = 0; r < 4; ++r) {
            const int jg = j0 + quad*4 + r;
            const bool diag = (jg == n);
#pragma unroll
            for (int nt = 0; nt < 4; ++nt) {
                float u = acc[nt][r] + bgv[nt];
                float g = 1.0f / (1.0f + __expf(-u));
                vals[nt][r] = diag ? gval[nt] : g * tval[nt][r];
            }
        }

        // score partials
#pragma unroll
        for (int z = 0; z < 4; ++z) {
            float pp[4];
#pragma unroll
            for (int r = 0; r < 4; ++r) {
                float s = 0.f;
#pragma unroll
                for (int nt = 0; nt < 4; ++nt)
                    s = fmaf(vals[nt][r], wa_reg[z][nt], s);
                pp[r] = red16(s);
            }
            if (l15 == z) {
#pragma unroll
                for (int r = 0; r < 4; ++r)
                    part[par][z][quad*4 + r][wid] = pp[r];
            }
        }
        __syncthreads();   // only barrier per chunk

        // redundant lane-parallel softmax
        float scl0, scl1, scl2, scl3;
        {
            f32x4 pr = *(const f32x4*)&part[par][zg][jj][0];
            float s = cz_r + ((pr.x + pr.y) + (pr.z + pr.w));
            float e = s > 0.f ? s : 0.2f * s;
            float mx = red16max(e);
            float m_new = fmaxf(m_r, mx);
            float at = __expf(e - m_new);
            float ss = red16(at);
            float scale = __expf(m_r - m_new);
            l_r = l_r * scale + ss;
            m_r = m_new;
            alpha_w[wid][jj][zg] = at;
            scl0 = __shfl(scale, 0);
            scl1 = __shfl(scale, 16);
            scl2 = __shfl(scale, 32);
            scl3 = __shfl(scale, 48);
        }
#pragma unroll
        for (int nt = 0; nt < 4; ++nt) {
            vacc[0][nt] *= scl0; vacc[1][nt] *= scl1;
            vacc[2][nt] *= scl2; vacc[3][nt] *= scl3;
        }
#pragma unroll
        for (int r = 0; r < 4; ++r) {
            f32x4 al = *(const f32x4*)&alpha_w[wid][quad*4 + r][0];
#pragma unroll
            for (int nt = 0; nt < 4; ++nt) {
                float v = vals[nt][r];
                vacc[0][nt] = fmaf(al.x, v, vacc[0][nt]);
                vacc[1][nt] = fmaf(al.y, v, vacc[1][nt]);
                vacc[2][nt] = fmaf(al.z, v, vacc[2][nt]);
                vacc[3][nt] = fmaf(al.w, v, vacc[3][nt]);
            }
        }
    }

    // cross-quad reduce, write PV + ML
#pragma unroll
    for (int z = 0; z < 4; ++z)
#pragma unroll
        for (int nt = 0; nt < 4; ++nt)
            vred[quad*4 + z][hcol[nt]] = vacc[z][nt];
    __syncthreads();
#pragma unroll
    for (int z = 0; z < 4; ++z) {
        float s = (vred[0*4+z][t] + vred[1*4+z][t]) + (vred[2*4+z][t] + vred[3*4+z][t]);
        PV[((size_t)(hh*4 + z)*NN + n)*HH + t] = s;
    }
    if (wid == 0 && l15 == 0) {
        ML[((hh*4 + zg)*NN + n)*2 + 0] = m_r;
        ML[((hh*4 + zg)*NN + n)*2 + 1] = l_r;
    }
}

// grid 64: (16 n-tiles) x (4 f-tiles of 64). Fused 2-half merge + split-bf16 MFMA.
__global__ __launch_bounds__(256) void gat_out_kernel(
    const float* __restrict__ bias, const float* __restrict__ ws,
    float* __restrict__ out)
{
    const int n0 = (blockIdx.x >> 2) * 16;
    const int f0 = (blockIdx.x & 3) * 64;
    const int t    = threadIdx.x;
    const int wid  = t >> 6;
    const int lane = t & 63;
    const int quad = lane >> 4;
    const int l15  = lane & 15;

    const float* PV = ws + WS_PV;
    const float* ML = ws + WS_ML;
    const ushort* W2hi = (const ushort*)(ws + WS_W2H);
    const ushort* W2lo = (const ushort*)(ws + WS_W2L);

    __shared__ __align__(16) float redc[3*4*16*16];
    __shared__ __align__(16) float sq[16][4][2];

    // merge scales: t = n_i*8 + z*2 + q (t < 128); q-pairs adjacent lanes
    if (t < 128) {
        const int n_i = t >> 3, z = (t >> 1) & 3, q = t & 1;
        float m = ML[((q*4 + z)*NN + n0 + n_i)*2 + 0];
        float l = ML[((q*4 + z)*NN + n0 + n_i)*2 + 1];
        float mm = fmaxf(m, __shfl_xor(m, 1));
        float s  = __expf(m - mm);
        float ls = l * s;
        ls += __shfl_xor(ls, 1);
        sq[n_i][z][q] = s / ls;
    }
    __syncthreads();

    // wave wid owns z=wid (k stripe [wid*256,+256)); A-frags in registers
    f32x4 acc[4];
#pragma unroll
    for (int nt = 0; nt < 4; ++nt) acc[nt] = (f32x4){0.f,0.f,0.f,0.f};

    const float s0 = sq[l15][wid][0];
    const float s1 = sq[l15][wid][1];
    const float* pv0 = PV + ((size_t)(0*4 + wid)*NN + n0 + l15)*HH;
    const float* pv1 = PV + ((size_t)(1*4 + wid)*NN + n0 + l15)*HH;

    for (int ks = 0; ks < 8; ++ks) {
        const int kp = ks*32 + quad*8;
        f32x4 p0a = *(const f32x4*)(pv0 + kp);
        f32x4 p0b = *(const f32x4*)(pv0 + kp + 4);
        f32x4 p1a = *(const f32x4*)(pv1 + kp);
        f32x4 p1b = *(const f32x4*)(pv1 + kp + 4);
        float v[8];
        v[0] = s0*p0a.x + s1*p1a.x; v[1] = s0*p0a.y + s1*p1a.y;
        v[2] = s0*p0a.z + s1*p1a.z; v[3] = s0*p0a.w + s1*p1a.w;
        v[4] = s0*p0b.x + s1*p1b.x; v[5] = s0*p0b.y + s1*p1b.y;
        v[6] = s0*p0b.z + s1*p1b.z; v[7] = s0*p0b.w + s1*p1b.w;
        ushort hi[8], lo[8];
#pragma unroll
        for (int c = 0; c < 8; ++c) {
            hi[c] = f2bf(v[c]);
            lo[c] = f2bf(v[c] - bf2f(hi[c]));
        }
        short8 ah = *(short8*)hi;
        short8 al = *(short8*)lo;
        const int kg = wid*256 + kp;
#pragma unroll
        for (int nt = 0; nt < 4; ++nt) {
            const size_t boff = (size_t)(f0 + nt*16 + l15)*1024 + kg;
            short8 bh = *(const short8*)(W2hi + boff);
            short8 bl = *(const short8*)(W2lo + boff);
            acc[nt] = __builtin_amdgcn_mfma_f32_16x16x32_bf16(ah, bh, acc[nt], 0, 0, 0);
            acc[nt] = __builtin_amdgcn_mfma_f32_16x16x32_bf16(ah, bl, acc[nt], 0, 0, 0);
            acc[nt] = __builtin_amdgcn_mfma_f32_16x16x32_bf16(al, bh, acc[nt], 0, 0, 0);
        }
    }
    __syncthreads();

    if (wid > 0) {
#pragma unroll
        for (int nt = 0; nt < 4; ++nt)
#pragma unroll
            for (int r = 0; r < 4; ++r)
                redc[(((wid-1)*4 + nt)*16 + quad*4 + r)*16 + l15] = acc[nt][r];
    }
    __syncthreads();
    if (wid == 0) {
#pragma unroll
        for (int nt = 0; nt < 4; ++nt) {
            const int f = f0 + nt*16 + l15;
            float bv = bias[f];
#pragma unroll
            for (int r = 0; r < 4; ++r) {
                const int row = quad*4 + r;
                float s = acc[nt][r]
                        + redc[((0*4 + nt)*16 + row)*16 + l15]
                        + redc[((1*4 + nt)*16 + row)*16 + l15]
                        + redc[((2*4 + nt)*16 + row)*16 + l15];
                out[(size_t)(n0 + row)*HH + f] = fmaxf(0.25f * s, 0.f) + bv;
            }
        }
    }
}

extern "C" void kernel_launch(void* const* d_in, const int* in_sizes, int n_in,
                              void* d_out, int out_size, void* d_ws, size_t ws_size,
                              hipStream_t stream)
{
    const float* ahs    = (const float*)d_in[0];
    const float* ghs    = (const float*)d_in[1];
    const float* goal   = (const float*)d_in[2];
    const float* action = (const float*)d_in[3];
    const float* Wd     = (const float*)d_in[4];
    const float* b_dist = (const float*)d_in[5];
    const float* Wg     = (const float*)d_in[6];
    const float* b_gate = (const float*)d_in[7];
    const float* w      = (const float*)d_in[8];
    const float* a      = (const float*)d_in[9];
    const float* bias   = (const float*)d_in[10];
    float* ws   = (float*)d_ws;     // needs 3,596,288 bytes
    float* outp = (float*)d_out;

    precompute_kernel<<<272, 256, 0, stream>>>(ahs, goal, action, Wd, b_dist, Wg, w, a, ws);
    gat_partial_kernel<<<512, 256, 0, stream>>>(ahs, ghs, b_gate, ws);
    gat_out_kernel<<<64, 256, 0, stream>>>(bias, ws, outp);
}